// Round 2
// baseline (84.719 us; speedup 1.0000x reference)
//
#include <hip/hip_runtime.h>
#include <hip/hip_bf16.h>
#include <stdint.h>

#define MDIM 1024
#define NDIM 4096
#define KDIM 4096

#define BM 128
#define BN 128
#define BK 64

typedef __attribute__((ext_vector_type(4))) float f32x4;
typedef __attribute__((ext_vector_type(4))) float float4v;
typedef __attribute__((ext_vector_type(4))) int int4v;
typedef __attribute__((ext_vector_type(4))) unsigned int uint4v;
typedef __attribute__((ext_vector_type(8))) short short8;

#define GLOBAL_AS __attribute__((address_space(1)))
#define LDS_AS __attribute__((address_space(3)))

// Compiler-level memory fence (IR) — s_barrier builtin alone is NOT a fence.
#define CFENCE asm volatile("" ::: "memory")
// Full barrier with both-side fences + machine-scheduler pin.
#define HARD_BARRIER() do {                      \
    CFENCE;                                      \
    __builtin_amdgcn_s_barrier();                \
    CFENCE;                                      \
    __builtin_amdgcn_sched_barrier(0);           \
} while (0)

__device__ __constant__ float c_nf4[16] = {
    -1.0f, -0.6961928009986877f, -0.5250730514526367f, -0.39491748809814453f,
    -0.28444138169288635f, -0.18477343022823334f, -0.09105003625154495f, 0.0f,
    0.07958029955625534f, 0.16093020141124725f, 0.24611230194568634f,
    0.33791524171829224f, 0.44070982933044434f, 0.5626170039176941f,
    0.7229568362236023f, 1.0f};

__device__ __forceinline__ unsigned bf16_rne(float f) {
    unsigned u = __float_as_uint(f);
    return (u + 0x7fffu + ((u >> 16) & 1u)) >> 16;
}

// ---------------------------------------------------------------------------
// Prep: Wc[n][k] = bf16(w0[n][k] + NF4[idx[n][k]]*scale + zp)   (8192 blocks)
//       xb[m][k] = bf16(x[m][k])                                 (2048 blocks)
// ---------------------------------------------------------------------------
#define W_BLOCKS ((NDIM * KDIM) / (256 * 8))   // 8192
#define X_BLOCKS ((MDIM * KDIM) / (256 * 8))   // 2048

__global__ __launch_bounds__(256) void prep_kernel(
    const float* __restrict__ x, const float* __restrict__ w0,
    const int* __restrict__ nf4_idx, const float* __restrict__ scale_p,
    const float* __restrict__ zp_p, __hip_bfloat16* __restrict__ Wc,
    __hip_bfloat16* __restrict__ xb)
{
    const int lane = threadIdx.x & 63;
    if (blockIdx.x < W_BLOCKS) {
        const float scale = scale_p[0];
        const float zp = zp_p[0];
        // lane-resident table: lane l holds NF4[l&15]*scale + zp
        const int tab = __float_as_int(c_nf4[lane & 15] * scale + zp);
        const size_t base = ((size_t)blockIdx.x * 256 + threadIdx.x) * 8;
        int4v i0 = *(const int4v*)(nf4_idx + base);
        int4v i1 = *(const int4v*)(nf4_idx + base + 4);
        float4v w_0 = *(const float4v*)(w0 + base);
        float4v w_1 = *(const float4v*)(w0 + base + 4);
        unsigned r[8];
#pragma unroll
        for (int j = 0; j < 4; j++) {
            float q = __int_as_float(__builtin_amdgcn_ds_bpermute(i0[j] * 4, tab));
            r[j] = bf16_rne(w_0[j] + q);
        }
#pragma unroll
        for (int j = 0; j < 4; j++) {
            float q = __int_as_float(__builtin_amdgcn_ds_bpermute(i1[j] * 4, tab));
            r[4 + j] = bf16_rne(w_1[j] + q);
        }
        uint4v st;
        st.x = r[0] | (r[1] << 16);
        st.y = r[2] | (r[3] << 16);
        st.z = r[4] | (r[5] << 16);
        st.w = r[6] | (r[7] << 16);
        *(uint4v*)((unsigned short*)Wc + base) = st;
    } else {
        const size_t base = ((size_t)(blockIdx.x - W_BLOCKS) * 256 + threadIdx.x) * 8;
        float4v a0 = *(const float4v*)(x + base);
        float4v a1 = *(const float4v*)(x + base + 4);
        uint4v st;
        st.x = bf16_rne(a0[0]) | (bf16_rne(a0[1]) << 16);
        st.y = bf16_rne(a0[2]) | (bf16_rne(a0[3]) << 16);
        st.z = bf16_rne(a1[0]) | (bf16_rne(a1[1]) << 16);
        st.w = bf16_rne(a1[2]) | (bf16_rne(a1[3]) << 16);
        *(uint4v*)((unsigned short*)xb + base) = st;
    }
}

// ---------------------------------------------------------------------------
// GEMM: C[m][n] = sum_k A[m][k] * B[n][k]   (A,B bf16 row-major, C fp32)
// 128x128 tile, BK=64, 4 waves (2x2 of 64x64), 16x16x32 MFMA, double-buffered
// LDS with counted vmcnt, XOR chunk swizzle (chunk ^= row&7) for conflict-free
// ds_read_b128 (swizzle applied on the *global source* address; LDS linear).
// ---------------------------------------------------------------------------
__global__ __launch_bounds__(256) void gemm_kernel(
    const __hip_bfloat16* __restrict__ A,   // [MDIM][KDIM]
    const __hip_bfloat16* __restrict__ B,   // [NDIM][KDIM]
    float* __restrict__ C)                  // [MDIM][NDIM]
{
    __shared__ __hip_bfloat16 sm[2][2][BM * BK];  // 64 KiB

    const int tid = threadIdx.x;
    const int lane = tid & 63;
    const int w = tid >> 6;          // wave 0..3
    const int wr = w >> 1;           // wave row (M)
    const int wc = w & 1;            // wave col (N)
    const int mtile = blockIdx.x;    // 0..7
    const int ntile = blockIdx.y;    // 0..31

    // --- staging addresses (per-lane global source, pre-swizzled) ---
    // wave w stages rows [w*32, w*32+32) of both A-tile and B-tile,
    // 4 instructions each (8 rows / instr, lane covers row=base+l/8, chunk=l%8)
    const int s_subrow = lane >> 3;          // 0..7
    const int s_chunkpos = lane & 7;         // LDS chunk position
    int s_row[4], s_goff[4];
#pragma unroll
    for (int j = 0; j < 4; j++) {
        int row = w * 32 + j * 8 + s_subrow;
        s_row[j] = row;
        int gchunk = s_chunkpos ^ (row & 7);  // content chunk for this slot
        s_goff[j] = gchunk * 8;               // element offset within row
    }

#define STAGE(buf, kt) do {                                                        \
    _Pragma("unroll")                                                              \
    for (int j = 0; j < 4; j++) {                                                  \
        const __hip_bfloat16* ga = A + (size_t)(mtile * BM + s_row[j]) * KDIM      \
                                     + (kt) * BK + s_goff[j];                      \
        __builtin_amdgcn_global_load_lds((const GLOBAL_AS void*)ga,                \
            (LDS_AS void*)&sm[buf][0][(w * 32 + j * 8) * BK], 16, 0, 0);           \
        const __hip_bfloat16* gb = B + (size_t)(ntile * BN + s_row[j]) * KDIM      \
                                     + (kt) * BK + s_goff[j];                      \
        __builtin_amdgcn_global_load_lds((const GLOBAL_AS void*)gb,                \
            (LDS_AS void*)&sm[buf][1][(w * 32 + j * 8) * BK], 16, 0, 0);           \
    }                                                                              \
} while (0)

    // --- fragment LDS element offsets (swizzled reads) ---
    int a_off[2][4], b_off[2][4];
#pragma unroll
    for (int kk2 = 0; kk2 < 2; kk2++) {
#pragma unroll
        for (int m = 0; m < 4; m++) {
            int row = wr * 64 + m * 16 + (lane & 15);
            int ch = (kk2 * 4 + (lane >> 4)) ^ (row & 7);
            a_off[kk2][m] = row * BK + ch * 8;
        }
#pragma unroll
        for (int n = 0; n < 4; n++) {
            int row = wc * 64 + n * 16 + (lane & 15);
            int ch = (kk2 * 4 + (lane >> 4)) ^ (row & 7);
            b_off[kk2][n] = row * BK + ch * 8;
        }
    }

    f32x4 acc[4][4] = {};

#define COMPUTE(buf) do {                                                          \
    _Pragma("unroll")                                                              \
    for (int kk2 = 0; kk2 < 2; kk2++) {                                            \
        short8 af[4], bfv[4];                                                      \
        _Pragma("unroll")                                                          \
        for (int m = 0; m < 4; m++)                                                \
            af[m] = *(const short8*)&sm[buf][0][a_off[kk2][m]];                    \
        _Pragma("unroll")                                                          \
        for (int n = 0; n < 4; n++)                                                \
            bfv[n] = *(const short8*)&sm[buf][1][b_off[kk2][n]];                   \
        _Pragma("unroll")                                                          \
        for (int m = 0; m < 4; m++)                                                \
            _Pragma("unroll")                                                      \
            for (int n = 0; n < 4; n++)                                            \
                acc[m][n] = __builtin_amdgcn_mfma_f32_16x16x32_bf16(               \
                    af[m], bfv[n], acc[m][n], 0, 0, 0);                            \
    }                                                                              \
} while (0)

    const int NT = KDIM / BK;  // 64
    STAGE(0, 0);

    for (int t = 0; t < NT; t++) {
        const int cur = t & 1;
        // (a) all waves done ds_read-ing buf[cur^1] from iteration t-1.
        // Fences on BOTH sides: s_barrier builtin is not a memory fence, and
        // without the post-fence LLVM can hoist STAGE's global_load_lds above
        // the barrier -> LDS write races readers (manifests only when L2-warm).
        HARD_BARRIER();
        if (t + 1 < NT) {
            STAGE(cur ^ 1, t + 1);             // prefetch next tile
            asm volatile("s_waitcnt vmcnt(8)" ::: "memory");  // stage(t) landed
        } else {
            asm volatile("s_waitcnt vmcnt(0)" ::: "memory");
        }
        // (b) every wave's stage(t) landed in LDS.
        HARD_BARRIER();
        COMPUTE(cur);
    }

    // --- epilogue: C/D layout col = lane&15, row = (lane>>4)*4 + r ---
    const int rbase = mtile * BM + wr * 64 + ((lane >> 4) << 2);
    const int cbase = ntile * BN + wc * 64 + (lane & 15);
#pragma unroll
    for (int m = 0; m < 4; m++) {
#pragma unroll
        for (int n = 0; n < 4; n++) {
#pragma unroll
            for (int r = 0; r < 4; r++) {
                C[(size_t)(rbase + m * 16 + r) * NDIM + cbase + n * 16] =
                    acc[m][n][r];
            }
        }
    }
#undef STAGE
#undef COMPUTE
}

// ---------------------------------------------------------------------------
// Fallback (only if ws too small): textbook fp32 tiled GEMM with inline dequant
// ---------------------------------------------------------------------------
__global__ void fallback_kernel(const float* __restrict__ x,
                                const float* __restrict__ w0,
                                const int* __restrict__ nf4_idx,
                                const float* __restrict__ sp,
                                const float* __restrict__ zpp,
                                float* __restrict__ out)
{
    __shared__ float As[16][16], Bs[16][17];
    const int tx = threadIdx.x, ty = threadIdx.y;
    const int n0 = blockIdx.x * 16, m0 = blockIdx.y * 16;
    const float s = sp[0], zp = zpp[0];
    float acc = 0.0f;
    for (int k0 = 0; k0 < KDIM; k0 += 16) {
        As[ty][tx] = x[(size_t)(m0 + ty) * KDIM + k0 + tx];
        int id = nf4_idx[(size_t)(n0 + ty) * KDIM + k0 + tx];
        Bs[ty][tx] = w0[(size_t)(n0 + ty) * KDIM + k0 + tx] + c_nf4[id] * s + zp;
        __syncthreads();
#pragma unroll
        for (int j = 0; j < 16; j++) acc += As[ty][j] * Bs[tx][j];
        __syncthreads();
    }
    out[(size_t)(m0 + ty) * NDIM + n0 + tx] = acc;
}

extern "C" void kernel_launch(void* const* d_in, const int* in_sizes, int n_in,
                              void* d_out, int out_size, void* d_ws, size_t ws_size,
                              hipStream_t stream) {
    const float* x = (const float*)d_in[0];
    const float* w0 = (const float*)d_in[1];
    const int* nf4_idx = (const int*)d_in[2];
    const float* scale = (const float*)d_in[3];
    const float* zp = (const float*)d_in[4];
    float* out = (float*)d_out;

    const size_t wc_bytes = (size_t)NDIM * KDIM * 2;       // 33,554,432
    const size_t xb_bytes = (size_t)MDIM * KDIM * 2;       //  8,388,608

    if (ws_size >= wc_bytes + xb_bytes) {
        __hip_bfloat16* Wc = (__hip_bfloat16*)d_ws;
        __hip_bfloat16* xb = (__hip_bfloat16*)((char*)d_ws + wc_bytes);
        prep_kernel<<<W_BLOCKS + X_BLOCKS, 256, 0, stream>>>(
            x, w0, nf4_idx, scale, zp, Wc, xb);
        gemm_kernel<<<dim3(MDIM / BM, NDIM / BN), 256, 0, stream>>>(xb, Wc, out);
    } else {
        fallback_kernel<<<dim3(NDIM / 16, MDIM / 16), dim3(16, 16), 0, stream>>>(
            x, w0, nf4_idx, scale, zp, out);
    }
}

// Round 3
// 71.285 us; speedup vs baseline: 1.1885x; 1.1885x over previous
//
#include <hip/hip_runtime.h>
#include <hip/hip_bf16.h>
#include <stdint.h>

#define MDIM 1024
#define NDIM 4096
#define KDIM 4096

#define BM 128
#define BN 128
#define BK 64

typedef __attribute__((ext_vector_type(4))) float f32x4;
typedef __attribute__((ext_vector_type(4))) float float4v;
typedef __attribute__((ext_vector_type(4))) int int4v;
typedef __attribute__((ext_vector_type(4))) unsigned int uint4v;
typedef __attribute__((ext_vector_type(8))) short short8;

#define GLOBAL_AS __attribute__((address_space(1)))
#define LDS_AS __attribute__((address_space(3)))

// Compiler-level memory fence (IR) — s_barrier builtin alone is NOT a fence.
#define CFENCE asm volatile("" ::: "memory")
#define HARD_BARRIER() do {                      \
    CFENCE;                                      \
    __builtin_amdgcn_s_barrier();                \
    CFENCE;                                      \
    __builtin_amdgcn_sched_barrier(0);           \
} while (0)

__device__ __constant__ float c_nf4[16] = {
    -1.0f, -0.6961928009986877f, -0.5250730514526367f, -0.39491748809814453f,
    -0.28444138169288635f, -0.18477343022823334f, -0.09105003625154495f, 0.0f,
    0.07958029955625534f, 0.16093020141124725f, 0.24611230194568634f,
    0.33791524171829224f, 0.44070982933044434f, 0.5626170039176941f,
    0.7229568362236023f, 1.0f};

__device__ __forceinline__ unsigned bf16_rne(float f) {
    unsigned u = __float_as_uint(f);
    return (u + 0x7fffu + ((u >> 16) & 1u)) >> 16;
}

// ---------------------------------------------------------------------------
// Prep: Wc[n][k] = bf16(w0[n][k] + NF4[idx[n][k]]*scale + zp)
//       xb[m][k] = bf16(x[m][k])
// ---------------------------------------------------------------------------
#define W_BLOCKS ((NDIM * KDIM) / (256 * 8))   // 8192
#define X_BLOCKS ((MDIM * KDIM) / (256 * 8))   // 2048

__global__ __launch_bounds__(256) void prep_kernel(
    const float* __restrict__ x, const float* __restrict__ w0,
    const int* __restrict__ nf4_idx, const float* __restrict__ scale_p,
    const float* __restrict__ zp_p, __hip_bfloat16* __restrict__ Wc,
    __hip_bfloat16* __restrict__ xb)
{
    const int lane = threadIdx.x & 63;
    if (blockIdx.x < W_BLOCKS) {
        const float scale = scale_p[0];
        const float zp = zp_p[0];
        const int tab = __float_as_int(c_nf4[lane & 15] * scale + zp);
        const size_t base = ((size_t)blockIdx.x * 256 + threadIdx.x) * 8;
        int4v i0 = *(const int4v*)(nf4_idx + base);
        int4v i1 = *(const int4v*)(nf4_idx + base + 4);
        float4v w_0 = *(const float4v*)(w0 + base);
        float4v w_1 = *(const float4v*)(w0 + base + 4);
        unsigned r[8];
#pragma unroll
        for (int j = 0; j < 4; j++) {
            float q = __int_as_float(__builtin_amdgcn_ds_bpermute(i0[j] * 4, tab));
            r[j] = bf16_rne(w_0[j] + q);
        }
#pragma unroll
        for (int j = 0; j < 4; j++) {
            float q = __int_as_float(__builtin_amdgcn_ds_bpermute(i1[j] * 4, tab));
            r[4 + j] = bf16_rne(w_1[j] + q);
        }
        uint4v st;
        st.x = r[0] | (r[1] << 16);
        st.y = r[2] | (r[3] << 16);
        st.z = r[4] | (r[5] << 16);
        st.w = r[6] | (r[7] << 16);
        *(uint4v*)((unsigned short*)Wc + base) = st;
    } else {
        const size_t base = ((size_t)(blockIdx.x - W_BLOCKS) * 256 + threadIdx.x) * 8;
        float4v a0 = *(const float4v*)(x + base);
        float4v a1 = *(const float4v*)(x + base + 4);
        uint4v st;
        st.x = bf16_rne(a0[0]) | (bf16_rne(a0[1]) << 16);
        st.y = bf16_rne(a0[2]) | (bf16_rne(a0[3]) << 16);
        st.z = bf16_rne(a1[0]) | (bf16_rne(a1[1]) << 16);
        st.w = bf16_rne(a1[2]) | (bf16_rne(a1[3]) << 16);
        *(uint4v*)((unsigned short*)xb + base) = st;
    }
}

// ---------------------------------------------------------------------------
// GEMM: C[m][n] = sum_k A[m][k] * B[n][k]   (A,B bf16 row-major, C fp32)
// 128x128 tile, BK=64, 8 waves (2x4 of 64x32), 16x16x32 MFMA.
// Triple-buffered LDS, prefetch distance 2, counted vmcnt(8) (per-wave:
// 4 loads/stage x 2 tiles in flight). XOR chunk swizzle via pre-swizzled
// global source (LDS linear, rule #21). XCD remap: each XCD owns 4 ntiles.
// ---------------------------------------------------------------------------
__global__ __launch_bounds__(512) void gemm_kernel(
    const __hip_bfloat16* __restrict__ A,   // [MDIM][KDIM]
    const __hip_bfloat16* __restrict__ B,   // [NDIM][KDIM]
    float* __restrict__ C)                  // [MDIM][NDIM]
{
    __shared__ __hip_bfloat16 sm[3][2][BM * BK];  // 96 KiB

    const int tid = threadIdx.x;
    const int lane = tid & 63;
    const int w = tid >> 6;          // wave 0..7
    const int wr = w >> 2;           // wave row (M): 0..1  -> 64 rows
    const int wc = w & 3;            // wave col (N): 0..3  -> 32 cols

    // XCD remap: default assignment is round-robin (xcd = bid % 8).
    // orig = (bid%8)*32 + bid/8 gives XCD x the 32 blocks covering
    // ntiles [x*4, x*4+4) x all 8 mtiles -> B panels L2-resident per XCD.
    const int bid = blockIdx.x;
    const int orig = (bid & 7) * 32 + (bid >> 3);
    const int mtile = orig & 7;      // 0..7
    const int ntile = orig >> 3;     // 0..31

    // --- staging addresses (per-lane global source, pre-swizzled) ---
    // wave w stages rows [w*16, w*16+16) of A-tile and B-tile: 2 instrs each
    // (8 rows / instr; lane covers row = base + lane/8, chunk slot = lane%8)
    const int s_subrow = lane >> 3;
    const int s_chunkpos = lane & 7;
    int s_row[2], s_goff[2];
#pragma unroll
    for (int j = 0; j < 2; j++) {
        int row = w * 16 + j * 8 + s_subrow;
        s_row[j] = row;
        int gchunk = s_chunkpos ^ (row & 7);   // content chunk for this slot
        s_goff[j] = gchunk * 8;                // element offset within row
    }

#define STAGE(buf, kt) do {                                                        \
    _Pragma("unroll")                                                              \
    for (int j = 0; j < 2; j++) {                                                  \
        const __hip_bfloat16* ga = A + (size_t)(mtile * BM + s_row[j]) * KDIM      \
                                     + (kt) * BK + s_goff[j];                      \
        __builtin_amdgcn_global_load_lds((const GLOBAL_AS void*)ga,                \
            (LDS_AS void*)&sm[buf][0][(w * 16 + j * 8) * BK], 16, 0, 0);           \
        const __hip_bfloat16* gb = B + (size_t)(ntile * BN + s_row[j]) * KDIM      \
                                     + (kt) * BK + s_goff[j];                      \
        __builtin_amdgcn_global_load_lds((const GLOBAL_AS void*)gb,                \
            (LDS_AS void*)&sm[buf][1][(w * 16 + j * 8) * BK], 16, 0, 0);           \
    }                                                                              \
} while (0)

    // --- fragment LDS element offsets (swizzled reads) ---
    int a_off[2][4], b_off[2][2];
#pragma unroll
    for (int kk2 = 0; kk2 < 2; kk2++) {
#pragma unroll
        for (int m = 0; m < 4; m++) {
            int row = wr * 64 + m * 16 + (lane & 15);
            int ch = (kk2 * 4 + (lane >> 4)) ^ (row & 7);
            a_off[kk2][m] = row * BK + ch * 8;
        }
#pragma unroll
        for (int n = 0; n < 2; n++) {
            int row = wc * 32 + n * 16 + (lane & 15);
            int ch = (kk2 * 4 + (lane >> 4)) ^ (row & 7);
            b_off[kk2][n] = row * BK + ch * 8;
        }
    }

    f32x4 acc[4][2] = {};

#define COMPUTE(buf) do {                                                          \
    _Pragma("unroll")                                                              \
    for (int kk2 = 0; kk2 < 2; kk2++) {                                            \
        short8 af[4], bfv[2];                                                      \
        _Pragma("unroll")                                                          \
        for (int m = 0; m < 4; m++)                                                \
            af[m] = *(const short8*)&sm[buf][0][a_off[kk2][m]];                    \
        _Pragma("unroll")                                                          \
        for (int n = 0; n < 2; n++)                                                \
            bfv[n] = *(const short8*)&sm[buf][1][b_off[kk2][n]];                   \
        __builtin_amdgcn_s_setprio(1);                                             \
        _Pragma("unroll")                                                          \
        for (int m = 0; m < 4; m++)                                                \
            _Pragma("unroll")                                                      \
            for (int n = 0; n < 2; n++)                                            \
                acc[m][n] = __builtin_amdgcn_mfma_f32_16x16x32_bf16(               \
                    af[m], bfv[n], acc[m][n], 0, 0, 0);                            \
        __builtin_amdgcn_s_setprio(0);                                             \
    }                                                                              \
} while (0)

    const int NT = KDIM / BK;  // 64
    STAGE(0, 0);
    STAGE(1, 1);

    for (int t = 0; t < NT; t++) {
        const int cur = t % 3;
        // STAGE(t+2) overwrites buf[(t-1)%3]; reads of it completed at the
        // trailing barrier of iteration t-1 (we are after it).
        if (t + 2 < NT) {
            STAGE((t + 2) % 3, t + 2);
            // per-wave: stages t+1,t+2 in flight (8) -> oldest (stage t) landed
            asm volatile("s_waitcnt vmcnt(8)" ::: "memory");
        } else if (t + 1 < NT) {
            asm volatile("s_waitcnt vmcnt(4)" ::: "memory");
        } else {
            asm volatile("s_waitcnt vmcnt(0)" ::: "memory");
        }
        // all waves' stage(t) landed in LDS
        HARD_BARRIER();
        COMPUTE(cur);
        // all waves done reading buf[cur] before it is restaged next iter
        HARD_BARRIER();
    }

    // --- epilogue: C/D layout col = lane&15, row = (lane>>4)*4 + r ---
    const int rbase = mtile * BM + wr * 64 + ((lane >> 4) << 2);
    const int cbase = ntile * BN + wc * 32 + (lane & 15);
#pragma unroll
    for (int m = 0; m < 4; m++) {
#pragma unroll
        for (int n = 0; n < 2; n++) {
#pragma unroll
            for (int r = 0; r < 4; r++) {
                C[(size_t)(rbase + m * 16 + r) * NDIM + cbase + n * 16] =
                    acc[m][n][r];
            }
        }
    }
#undef STAGE
#undef COMPUTE
}

// ---------------------------------------------------------------------------
// Fallback (only if ws too small): textbook fp32 tiled GEMM with inline dequant
// ---------------------------------------------------------------------------
__global__ void fallback_kernel(const float* __restrict__ x,
                                const float* __restrict__ w0,
                                const int* __restrict__ nf4_idx,
                                const float* __restrict__ sp,
                                const float* __restrict__ zpp,
                                float* __restrict__ out)
{
    __shared__ float As[16][16], Bs[16][17];
    const int tx = threadIdx.x, ty = threadIdx.y;
    const int n0 = blockIdx.x * 16, m0 = blockIdx.y * 16;
    const float s = sp[0], zp = zpp[0];
    float acc = 0.0f;
    for (int k0 = 0; k0 < KDIM; k0 += 16) {
        As[ty][tx] = x[(size_t)(m0 + ty) * KDIM + k0 + tx];
        int id = nf4_idx[(size_t)(n0 + ty) * KDIM + k0 + tx];
        Bs[ty][tx] = w0[(size_t)(n0 + ty) * KDIM + k0 + tx] + c_nf4[id] * s + zp;
        __syncthreads();
#pragma unroll
        for (int j = 0; j < 16; j++) acc += As[ty][j] * Bs[tx][j];
        __syncthreads();
    }
    out[(size_t)(m0 + ty) * NDIM + n0 + tx] = acc;
}

extern "C" void kernel_launch(void* const* d_in, const int* in_sizes, int n_in,
                              void* d_out, int out_size, void* d_ws, size_t ws_size,
                              hipStream_t stream) {
    const float* x = (const float*)d_in[0];
    const float* w0 = (const float*)d_in[1];
    const int* nf4_idx = (const int*)d_in[2];
    const float* scale = (const float*)d_in[3];
    const float* zp = (const float*)d_in[4];
    float* out = (float*)d_out;

    const size_t wc_bytes = (size_t)NDIM * KDIM * 2;       // 33,554,432
    const size_t xb_bytes = (size_t)MDIM * KDIM * 2;       //  8,388,608

    if (ws_size >= wc_bytes + xb_bytes) {
        __hip_bfloat16* Wc = (__hip_bfloat16*)d_ws;
        __hip_bfloat16* xb = (__hip_bfloat16*)((char*)d_ws + wc_bytes);
        prep_kernel<<<W_BLOCKS + X_BLOCKS, 256, 0, stream>>>(
            x, w0, nf4_idx, scale, zp, Wc, xb);
        gemm_kernel<<<(MDIM / BM) * (NDIM / BN), 512, 0, stream>>>(xb, Wc, out);
    } else {
        fallback_kernel<<<dim3(NDIM / 16, MDIM / 16), dim3(16, 16), 0, stream>>>(
            x, w0, nf4_idx, scale, zp, out);
    }
}